// Round 7
// baseline (137.338 us; speedup 1.0000x reference)
//
#include <hip/hip_runtime.h>
#include <math.h>
#include <stdint.h>

#define NPROJ 16
#define NBINS 65536
#define WD (NBINS - 6)
#define HB 65560              // hist byte stride/bp: 8 front pad + 65536 + 16 back pad
#define B_ 2
#define C_ 3
#define H_ 384
#define W_ 384
#define HO 378
#define NPAT (HO * HO)        // 142884 (div by 4)
#define DF 147                // 3*7*7
#define BP 32                 // B_*NPROJ
#define TSTR 24               // LDS tile row stride

__device__ inline unsigned f2key(float f) {
    unsigned u = __float_as_uint(f);
    return (u & 0x80000000u) ? ~u : (u | 0x80000000u);
}
__device__ inline float key2f(unsigned k) {
    unsigned u = (k & 0x80000000u) ? (k ^ 0x80000000u) : ~k;
    return __uint_as_float(u);
}

// ---------- K0: rand/std (ddof=1); init keys; zero out -----------------------
__global__ __launch_bounds__(64) void k_rnorm(const float* __restrict__ rnd,
                                              float* __restrict__ rnorm,
                                              unsigned* __restrict__ keys,
                                              float* __restrict__ out) {
    int bp = blockIdx.x;
    int b = bp / NPROJ, p = bp % NPROJ;
    int lane = threadIdx.x;
    if (lane == 0) {
        keys[2 * bp] = 0xFFFFFFFFu;
        keys[2 * bp + 1] = 0u;
        if (bp == 0) out[0] = 0.f;     // accumulated atomically in k_gather8
    }
    float s = 0.f, s2 = 0.f;
    for (int d = lane; d < DF; d += 64) {
        float v = rnd[((size_t)b * DF + d) * NPROJ + p];
        s += v; s2 += v * v;
    }
    for (int o = 32; o > 0; o >>= 1) { s += __shfl_down(s, o); s2 += __shfl_down(s2, o); }
    s = __shfl(s, 0); s2 = __shfl(s2, 0);
    float mean = s / (float)DF;
    float var = (s2 - (float)DF * mean * mean) / (float)(DF - 1);
    float inv = 1.0f / sqrtf(var);
    for (int d = lane; d < DF; d += 64) {
        size_t idx = ((size_t)b * DF + d) * NPROJ + p;
        rnorm[idx] = rnd[idx] * inv;
    }
}

// ---------- K1: proj one image-tile; store proj; min/max atomics -------------
// 1 output/thread, tile 16x16, grid (24,24,4): z = b*2 + isy.
// Weights via wave-uniform global reads (s_load/K$) - no LDS for weights.
#define T1 16
__global__ __launch_bounds__(256) void k_projmm(const float* __restrict__ ximg,
                                                const float* __restrict__ yimg,
                                                const float* __restrict__ rnorm,
                                                float* __restrict__ px,
                                                float* __restrict__ py,
                                                unsigned* __restrict__ keys) {
    __shared__ float tile[C_][T1 + 6][TSTR];   // [3][22][24] = 6336 B
    __shared__ float red_mn[4][NPROJ], red_mx[4][NPROJ];
    int bz = blockIdx.z;
    int b = bz >> 1, isy = bz & 1;
    const float* img = isy ? yimg : ximg;
    float* proj = isy ? py : px;
    int tid = threadIdx.x;
    int tx = tid & 15, ty = tid >> 4;
    int h0 = blockIdx.y * T1, w0 = blockIdx.x * T1;

    for (int c = 0; c < C_; c++)
        for (int i = tid; i < (T1 + 6) * (T1 + 6); i += 256) {
            int r = i / (T1 + 6), col = i % (T1 + 6);
            int h = h0 + r, w = w0 + col;
            tile[c][r][col] = (h < H_ && w < W_)
                ? img[((size_t)(b * C_ + c) * H_ + h) * W_ + w] : 0.f;
        }
    __syncthreads();

    const float* wbase = rnorm + (size_t)b * DF * NPROJ;

    float acc[NPROJ];
#pragma unroll
    for (int p = 0; p < NPROJ; p++) acc[p] = 0.f;

    for (int c = 0; c < C_; c++)
        for (int i = 0; i < 7; i++)
#pragma unroll
            for (int j = 0; j < 7; j++) {
                const float* wrow = wbase + (c * 49 + i * 7 + j) * NPROJ; // uniform
                float wv[NPROJ];
#pragma unroll
                for (int p = 0; p < NPROJ; p++) wv[p] = wrow[p];          // s_load
                float pix = tile[c][ty + i][tx + j];
#pragma unroll
                for (int p = 0; p < NPROJ; p++)
                    acc[p] = fmaf(pix, wv[p], acc[p]);
            }

    int wo = w0 + tx, ho = h0 + ty;
    bool vm = (ho < HO) && (wo < HO);

    if (vm) {
        size_t n = (size_t)ho * HO + wo;
#pragma unroll
        for (int p = 0; p < NPROJ; p++)
            proj[((size_t)(b * NPROJ + p)) * NPAT + n] = acc[p];
    }

    float pmn[NPROJ], pmx[NPROJ];
#pragma unroll
    for (int p = 0; p < NPROJ; p++) {
        pmn[p] = vm ? acc[p] : INFINITY;
        pmx[p] = vm ? acc[p] : -INFINITY;
    }
#pragma unroll
    for (int o = 1; o < 64; o <<= 1) {
#pragma unroll
        for (int p = 0; p < NPROJ; p++) {
            pmn[p] = fminf(pmn[p], __shfl_xor(pmn[p], o));
            pmx[p] = fmaxf(pmx[p], __shfl_xor(pmx[p], o));
        }
    }
    int wv4 = tid >> 6;
    if ((tid & 63) == 0) {
#pragma unroll
        for (int p = 0; p < NPROJ; p++) { red_mn[wv4][p] = pmn[p]; red_mx[wv4][p] = pmx[p]; }
    }
    __syncthreads();
    if (tid < NPROJ) {
        float mn = fminf(fminf(red_mn[0][tid], red_mn[1][tid]),
                         fminf(red_mn[2][tid], red_mn[3][tid]));
        float mx = fmaxf(fmaxf(red_mx[0][tid], red_mx[1][tid]),
                         fmaxf(red_mx[2][tid], red_mx[3][tid]));
        atomicMin(&keys[2 * (b * NPROJ + tid)], f2key(mn));
        atomicMax(&keys[2 * (b * NPROJ + tid) + 1], f2key(mx));
    }
}

// ---------- K2: y-hist scatter into uint8 flags (idempotent byte stores) -----
__global__ __launch_bounds__(256) void k_scatter(const float* __restrict__ py,
                                                 const unsigned* __restrict__ keys,
                                                 uint8_t* __restrict__ hist8) {
    int bp = blockIdx.y;
    float mn = key2f(keys[2 * bp]);
    float sc = key2f(keys[2 * bp + 1]) - mn;
    const float4* src = (const float4*)(py + (size_t)bp * NPAT);
    uint8_t* h = hist8 + (size_t)bp * HB + 8;
    const int n4 = NPAT / 4;
    for (int i = blockIdx.x * blockDim.x + threadIdx.x; i < n4;
         i += gridDim.x * blockDim.x) {
        float4 v = src[i];
        int i0 = (int)floorf(65535.f * (v.x - mn) / sc);
        int i1 = (int)floorf(65535.f * (v.y - mn) / sc);
        int i2 = (int)floorf(65535.f * (v.z - mn) / sc);
        int i3 = (int)floorf(65535.f * (v.w - mn) / sc);
        h[min(max(i0, 0), 65535)] = 1;
        h[min(max(i1, 0), 65535)] = 1;
        h[min(max(i2, 0), 65535)] = 1;
        h[min(max(i3, 0), 65535)] = 1;
    }
}

// one bilinear sample with on-the-fly 7-tap conv from byte-flag hist
__device__ inline float gath8(const uint32_t* __restrict__ hw, float v,
                              float mn, float sc, const float g[7]) {
    float t = (v - mn) / sc;                  // in [0,1]
    float ix = t * (float)WD - 0.5f;
    float x0 = floorf(ix);
    float w1 = ix - x0;
    int x0i = (int)x0;                        // [-1, WD-1]
    int b0 = 8 + x0i;                         // byte off in slice, >= 7
    int d0 = b0 >> 2, off = b0 & 3;
    uint32_t u0 = hw[d0], u1 = hw[d0 + 1], u2 = hw[d0 + 2];
    uint64_t lo = (uint64_t)u0 | ((uint64_t)u1 << 32);
    int sh = off * 8;
    uint64_t w8 = (lo >> sh) | ((((uint64_t)u2) << 1) << (63 - sh));
    float f0 = (float)((uint32_t)(w8      ) & 1u);
    float f1 = (float)((uint32_t)(w8 >>  8) & 1u);
    float f2 = (float)((uint32_t)(w8 >> 16) & 1u);
    float f3 = (float)((uint32_t)(w8 >> 24) & 1u);
    float f4 = (float)((uint32_t)(w8 >> 32) & 1u);
    float f5 = (float)((uint32_t)(w8 >> 40) & 1u);
    float f6 = (float)((uint32_t)(w8 >> 48) & 1u);
    float f7 = (float)((uint32_t)(w8 >> 56) & 1u);
    float s0 = g[0] * f0 + g[1] * f1 + g[2] * f2 + g[3] * f3
             + g[4] * f4 + g[5] * f5 + g[6] * f6;
    float s1 = g[0] * f1 + g[1] * f2 + g[2] * f3 + g[3] * f4
             + g[4] * f5 + g[5] * f6 + g[6] * f7;
    s0 = fminf(s0, 1.f);
    s1 = fminf(s1, 1.f);
    float r0 = (x0i >= 0) ? s0 : 0.f;
    float r1 = (x0i + 1 < WD) ? s1 : 0.f;
    return r0 * (1.f - w1) + r1 * w1;
}

// ---------- K3: pure gather over px; one bp-slice per block.y ----------------
__global__ __launch_bounds__(256) void k_gather8(const float* __restrict__ px,
                                                 const unsigned* __restrict__ keys,
                                                 const uint8_t* __restrict__ hist8,
                                                 float* __restrict__ out) {
    int bp = blockIdx.y;
    float mn = key2f(keys[2 * bp]);
    float sc = key2f(keys[2 * bp + 1]) - mn;
    const float4* src = (const float4*)(px + (size_t)bp * NPAT);
    const uint32_t* hw = (const uint32_t*)(hist8 + (size_t)bp * HB);
    float g[7];
#pragma unroll
    for (int k = 0; k < 7; k++) {
        float d = (float)(k - 3);
        g[k] = expf(-(d * d) / 1.44f);   // exp((x)^2/(-2*1.2^2))**2
    }
    float acc = 0.f;
    const int n4 = NPAT / 4;
    for (int i = blockIdx.x * blockDim.x + threadIdx.x; i < n4;
         i += gridDim.x * blockDim.x) {
        float4 v = src[i];
        acc += gath8(hw, v.x, mn, sc, g);
        acc += gath8(hw, v.y, mn, sc, g);
        acc += gath8(hw, v.z, mn, sc, g);
        acc += gath8(hw, v.w, mn, sc, g);
    }
    for (int o = 32; o > 0; o >>= 1) acc += __shfl_down(acc, o);
    __shared__ float sred[4];
    int wv4 = threadIdx.x >> 6;
    if ((threadIdx.x & 63) == 0) sred[wv4] = acc;
    __syncthreads();
    if (threadIdx.x == 0) {
        float t = sred[0] + sred[1] + sred[2] + sred[3];
        atomicAdd(out, -t * (1.0f / 32.0f));
    }
}

extern "C" void kernel_launch(void* const* d_in, const int* in_sizes, int n_in,
                              void* d_out, int out_size, void* d_ws, size_t ws_size,
                              hipStream_t stream) {
    (void)in_sizes; (void)n_in; (void)out_size; (void)ws_size;
    const float* x = (const float*)d_in[0];
    const float* y = (const float*)d_in[1];
    const float* rnd = (const float*)d_in[2];
    float* out = (float*)d_out;

    float* ws = (float*)d_ws;
    float* rnorm = ws;                                     // 4704 floats
    float* px = rnorm + (size_t)B_ * DF * NPROJ;           // BP*NPAT floats
    float* py = px + (size_t)BP * NPAT;                    // BP*NPAT floats
    unsigned* keys = (unsigned*)(py + (size_t)BP * NPAT);  // 2*BP
    uint8_t* hist8 = (uint8_t*)(keys + 2 * BP);            // BP*HB bytes

    k_rnorm<<<BP, 64, 0, stream>>>(rnd, rnorm, keys, out);
    hipMemsetAsync(hist8, 0, (size_t)BP * HB, stream);

    dim3 g1(384 / T1, 384 / T1, 2 * B_);                   // (24,24,4)
    k_projmm<<<g1, 256, 0, stream>>>(x, y, rnorm, px, py, keys);

    k_scatter<<<dim3(70, BP), 256, 0, stream>>>(py, keys, hist8);

    k_gather8<<<dim3(70, BP), 256, 0, stream>>>(px, keys, hist8, out);
}

// Round 8
// 121.045 us; speedup vs baseline: 1.1346x; 1.1346x over previous
//
#include <hip/hip_runtime.h>
#include <math.h>
#include <stdint.h>

#define NPROJ 16
#define NBINS 65536
#define WD (NBINS - 6)
#define HB 65792              // byte-hist stride/bp: 8 pad + 65536 + pad, = 2056*32
#define BMW 2056              // bitmap u32 words per bp (8224 B)
#define B_ 2
#define C_ 3
#define H_ 384
#define W_ 384
#define HO 378
#define NPAT (HO * HO)        // 142884 (div by 4)
#define DF 147                // 3*7*7
#define BP 32                 // B_*NPROJ
#define TSTR 24               // LDS tile row stride

__device__ inline unsigned f2key(float f) {
    unsigned u = __float_as_uint(f);
    return (u & 0x80000000u) ? ~u : (u | 0x80000000u);
}
__device__ inline float key2f(unsigned k) {
    unsigned u = (k & 0x80000000u) ? (k ^ 0x80000000u) : ~k;
    return __uint_as_float(u);
}

// ---------- K0: rand/std (ddof=1); init keys; zero out -----------------------
__global__ __launch_bounds__(64) void k_rnorm(const float* __restrict__ rnd,
                                              float* __restrict__ rnorm,
                                              unsigned* __restrict__ keys,
                                              float* __restrict__ out) {
    int bp = blockIdx.x;
    int b = bp / NPROJ, p = bp % NPROJ;
    int lane = threadIdx.x;
    if (lane == 0) {
        keys[2 * bp] = 0xFFFFFFFFu;
        keys[2 * bp + 1] = 0u;
        if (bp == 0) out[0] = 0.f;     // accumulated atomically in k_gather
    }
    float s = 0.f, s2 = 0.f;
    for (int d = lane; d < DF; d += 64) {
        float v = rnd[((size_t)b * DF + d) * NPROJ + p];
        s += v; s2 += v * v;
    }
    for (int o = 32; o > 0; o >>= 1) { s += __shfl_down(s, o); s2 += __shfl_down(s2, o); }
    s = __shfl(s, 0); s2 = __shfl(s2, 0);
    float mean = s / (float)DF;
    float var = (s2 - (float)DF * mean * mean) / (float)(DF - 1);
    float inv = 1.0f / sqrtf(var);
    for (int d = lane; d < DF; d += 64) {
        size_t idx = ((size_t)b * DF + d) * NPROJ + p;
        rnorm[idx] = rnd[idx] * inv;
    }
}

// ---------- K1: proj both images (R6 geometry); store px AND py; min/max -----
// tile 32(h)x16(w), 256 threads, 2 outputs/thread. grid (24,12,4): z=b*2+isy.
// Weights via wave-uniform global reads (s_load/K$) - no LDS for weights.
#define T1H 32
#define T1W 16
__global__ __launch_bounds__(256) void k_projmm(const float* __restrict__ ximg,
                                                const float* __restrict__ yimg,
                                                const float* __restrict__ rnorm,
                                                float* __restrict__ px,
                                                float* __restrict__ py,
                                                unsigned* __restrict__ keys) {
    __shared__ float tile[C_][T1H + 6][TSTR];   // [3][38][24]
    __shared__ float red_mn[4][NPROJ], red_mx[4][NPROJ];
    int bz = blockIdx.z;
    int b = bz >> 1, isy = bz & 1;
    const float* img = isy ? yimg : ximg;
    float* proj = isy ? py : px;
    int tid = threadIdx.x;
    int tx = tid & 15, ty = tid >> 4;              // 16x16 threads, rows 16 apart
    int h0 = blockIdx.y * T1H, w0 = blockIdx.x * T1W;

    for (int c = 0; c < C_; c++)
        for (int i = tid; i < (T1H + 6) * (T1W + 6); i += 256) {
            int r = i / (T1W + 6), col = i % (T1W + 6);
            int h = h0 + r, w = w0 + col;
            tile[c][r][col] = (h < H_ && w < W_)
                ? img[((size_t)(b * C_ + c) * H_ + h) * W_ + w] : 0.f;
        }
    __syncthreads();

    const float* wbase = rnorm + (size_t)b * DF * NPROJ;

    float acc[2][NPROJ];
#pragma unroll
    for (int q = 0; q < 2; q++)
#pragma unroll
        for (int p = 0; p < NPROJ; p++) acc[q][p] = 0.f;

    for (int c = 0; c < C_; c++)
        for (int i = 0; i < 7; i++)
#pragma unroll
            for (int j = 0; j < 7; j++) {
                const float* wrow = wbase + (c * 49 + i * 7 + j) * NPROJ; // uniform
                float wv[NPROJ];
#pragma unroll
                for (int p = 0; p < NPROJ; p++) wv[p] = wrow[p];          // s_load
                float pix0 = tile[c][ty + i][tx + j];
                float pix1 = tile[c][ty + 16 + i][tx + j];
#pragma unroll
                for (int p = 0; p < NPROJ; p++) {
                    acc[0][p] = fmaf(pix0, wv[p], acc[0][p]);
                    acc[1][p] = fmaf(pix1, wv[p], acc[1][p]);
                }
            }

    int wo = w0 + tx;
    int ho0 = h0 + ty, ho1 = h0 + ty + 16;
    bool vm0 = (ho0 < HO) && (wo < HO);
    bool vm1 = (ho1 < HO) && (wo < HO);

    if (vm0) {
        size_t n = (size_t)ho0 * HO + wo;
#pragma unroll
        for (int p = 0; p < NPROJ; p++)
            proj[((size_t)(b * NPROJ + p)) * NPAT + n] = acc[0][p];
    }
    if (vm1) {
        size_t n = (size_t)ho1 * HO + wo;
#pragma unroll
        for (int p = 0; p < NPROJ; p++)
            proj[((size_t)(b * NPROJ + p)) * NPAT + n] = acc[1][p];
    }

    float pmn[NPROJ], pmx[NPROJ];
#pragma unroll
    for (int p = 0; p < NPROJ; p++) {
        float mn = INFINITY, mx = -INFINITY;
        if (vm0) { mn = acc[0][p]; mx = acc[0][p]; }
        if (vm1) { mn = fminf(mn, acc[1][p]); mx = fmaxf(mx, acc[1][p]); }
        pmn[p] = mn; pmx[p] = mx;
    }
#pragma unroll
    for (int o = 1; o < 64; o <<= 1) {
#pragma unroll
        for (int p = 0; p < NPROJ; p++) {
            pmn[p] = fminf(pmn[p], __shfl_xor(pmn[p], o));
            pmx[p] = fmaxf(pmx[p], __shfl_xor(pmx[p], o));
        }
    }
    int wv4 = tid >> 6;
    if ((tid & 63) == 0) {
#pragma unroll
        for (int p = 0; p < NPROJ; p++) { red_mn[wv4][p] = pmn[p]; red_mx[wv4][p] = pmx[p]; }
    }
    __syncthreads();
    if (tid < NPROJ) {
        float mn = fminf(fminf(red_mn[0][tid], red_mn[1][tid]),
                         fminf(red_mn[2][tid], red_mn[3][tid]));
        float mx = fmaxf(fmaxf(red_mx[0][tid], red_mx[1][tid]),
                         fmaxf(red_mx[2][tid], red_mx[3][tid]));
        atomicMin(&keys[2 * (b * NPROJ + tid)], f2key(mn));
        atomicMax(&keys[2 * (b * NPROJ + tid) + 1], f2key(mx));
    }
}

// ---------- K2: y-hist scatter into uint8 flags (idempotent byte stores) -----
__global__ __launch_bounds__(256) void k_scatter(const float* __restrict__ py,
                                                 const unsigned* __restrict__ keys,
                                                 uint8_t* __restrict__ hist8) {
    int bp = blockIdx.y;
    float mn = key2f(keys[2 * bp]);
    float sc = key2f(keys[2 * bp + 1]) - mn;
    const float4* src = (const float4*)(py + (size_t)bp * NPAT);
    uint8_t* h = hist8 + (size_t)bp * HB + 8;
    const int n4 = NPAT / 4;
    for (int i = blockIdx.x * blockDim.x + threadIdx.x; i < n4;
         i += gridDim.x * blockDim.x) {
        float4 v = src[i];
        int i0 = (int)floorf(65535.f * (v.x - mn) / sc);
        int i1 = (int)floorf(65535.f * (v.y - mn) / sc);
        int i2 = (int)floorf(65535.f * (v.z - mn) / sc);
        int i3 = (int)floorf(65535.f * (v.w - mn) / sc);
        h[min(max(i0, 0), 65535)] = 1;
        h[min(max(i1, 0), 65535)] = 1;
        h[min(max(i2, 0), 65535)] = 1;
        h[min(max(i3, 0), 65535)] = 1;
    }
}

// ---------- K2b: compress byte-hist -> bitmap (bit k = padded-byte k) --------
__global__ __launch_bounds__(256) void k_compress(const uint8_t* __restrict__ hist8,
                                                  uint32_t* __restrict__ bitmap) {
    int bp = blockIdx.y;
    const uint8_t* src = hist8 + (size_t)bp * HB;
    uint32_t* dst = bitmap + (size_t)bp * BMW;
    for (int d = blockIdx.x * blockDim.x + threadIdx.x; d < BMW;
         d += gridDim.x * blockDim.x) {
        const uint4* s = (const uint4*)(src + 32 * d);
        uint4 a = s[0], b = s[1];
        uint32_t u[8] = { a.x, a.y, a.z, a.w, b.x, b.y, b.z, b.w };
        uint32_t w = 0;
#pragma unroll
        for (int k = 0; k < 8; k++) {
            uint32_t nib = (u[k] | (u[k] >> 7) | (u[k] >> 14) | (u[k] >> 21)) & 0xFu;
            w |= nib << (4 * k);
        }
        dst[d] = w;
    }
}

// ---------- K3: gather via bitmap + 256-entry LDS LUT ------------------------
// one dword load per sample (u16-indexed window), one LDS float2 read.
__global__ __launch_bounds__(256) void k_gather(const float* __restrict__ px,
                                                const unsigned* __restrict__ keys,
                                                const uint32_t* __restrict__ bitmap,
                                                float* __restrict__ out) {
    __shared__ float2 lut[256];
    __shared__ float sred[4];
    int bp = blockIdx.y;
    int tid = threadIdx.x;

    float g[7];
#pragma unroll
    for (int k = 0; k < 7; k++) {
        float d = (float)(k - 3);
        g[k] = expf(-(d * d) / 1.44f);   // exp((x)^2/(-2*1.2^2))**2
    }
    {
        int m = tid;   // 256 threads -> one LUT entry each
        float f[8];
#pragma unroll
        for (int k = 0; k < 8; k++) f[k] = (float)((m >> k) & 1);
        float s0 = g[0] * f[0] + g[1] * f[1] + g[2] * f[2] + g[3] * f[3]
                 + g[4] * f[4] + g[5] * f[5] + g[6] * f[6];
        float s1 = g[0] * f[1] + g[1] * f[2] + g[2] * f[3] + g[3] * f[4]
                 + g[4] * f[5] + g[5] * f[6] + g[6] * f[7];
        lut[m] = make_float2(fminf(s0, 1.f), fminf(s1, 1.f));
    }
    __syncthreads();

    float mn = key2f(keys[2 * bp]);
    float sc = key2f(keys[2 * bp + 1]) - mn;
    const float4* src = (const float4*)(px + (size_t)bp * NPAT);
    const uint8_t* bm = (const uint8_t*)(bitmap + (size_t)bp * BMW);

    float acc = 0.f;
    const int n4 = NPAT / 4;
    for (int i = blockIdx.x * blockDim.x + threadIdx.x; i < n4;
         i += gridDim.x * blockDim.x) {
        float4 v4 = src[i];
        float vv[4] = { v4.x, v4.y, v4.z, v4.w };
#pragma unroll
        for (int j = 0; j < 4; j++) {
            float v = vv[j];
            float t = (v - mn) / sc;             // in [0,1]
            float ix = t * (float)WD - 0.5f;
            float x0 = floorf(ix);
            float w1 = ix - x0;
            int x0i = (int)x0;                   // [-1, WD-1]
            int bit0 = 8 + x0i;                  // [7, 65537]
            uint32_t u;
            __builtin_memcpy(&u, bm + 2 * (bit0 >> 4), 4);  // 2B-aligned dword
            uint32_t w8 = (u >> (bit0 & 15)) & 0xFFu;       // bits bit0..bit0+7
            float2 sv = lut[w8];
            float r0 = (x0i >= 0) ? sv.x : 0.f;
            float r1 = (x0i + 1 < WD) ? sv.y : 0.f;
            acc += r0 * (1.f - w1) + r1 * w1;
        }
    }
    for (int o = 32; o > 0; o >>= 1) acc += __shfl_down(acc, o);
    int wv4 = tid >> 6;
    if ((tid & 63) == 0) sred[wv4] = acc;
    __syncthreads();
    if (tid == 0) {
        float t = sred[0] + sred[1] + sred[2] + sred[3];
        atomicAdd(out, -t * (1.0f / 32.0f));
    }
}

extern "C" void kernel_launch(void* const* d_in, const int* in_sizes, int n_in,
                              void* d_out, int out_size, void* d_ws, size_t ws_size,
                              hipStream_t stream) {
    (void)in_sizes; (void)n_in; (void)out_size; (void)ws_size;
    const float* x = (const float*)d_in[0];
    const float* y = (const float*)d_in[1];
    const float* rnd = (const float*)d_in[2];
    float* out = (float*)d_out;

    float* ws = (float*)d_ws;
    float* rnorm = ws;                                     // 4704 floats
    float* px = rnorm + (size_t)B_ * DF * NPROJ;           // BP*NPAT floats
    float* py = px + (size_t)BP * NPAT;                    // BP*NPAT floats
    unsigned* keys = (unsigned*)(py + (size_t)BP * NPAT);  // 2*BP
    uint8_t* hist8 = (uint8_t*)(keys + 2 * BP);            // BP*HB bytes
    uint32_t* bitmap = (uint32_t*)(hist8 + (size_t)BP * HB); // BP*BMW u32

    k_rnorm<<<BP, 64, 0, stream>>>(rnd, rnorm, keys, out);
    hipMemsetAsync(hist8, 0, (size_t)BP * HB, stream);

    dim3 g1(384 / T1W, 384 / T1H, 2 * B_);                 // (24,12,4)
    k_projmm<<<g1, 256, 0, stream>>>(x, y, rnorm, px, py, keys);

    k_scatter<<<dim3(70, BP), 256, 0, stream>>>(py, keys, hist8);
    k_compress<<<dim3(9, BP), 256, 0, stream>>>(hist8, bitmap);
    k_gather<<<dim3(70, BP), 256, 0, stream>>>(px, keys, bitmap, out);
}

// Round 9
// 118.012 us; speedup vs baseline: 1.1638x; 1.0257x over previous
//
#include <hip/hip_runtime.h>
#include <math.h>
#include <stdint.h>

#define NPROJ 16
#define NBINS 65536
#define WD (NBINS - 6)
#define BMW 2056              // bitmap u32 words per bp (8224 B); bit k = old byte k
#define B_ 2
#define C_ 3
#define H_ 384
#define W_ 384
#define HO 378
#define NPAT (HO * HO)        // 142884 (div by 4)
#define DF 147                // 3*7*7
#define BP 32                 // B_*NPROJ
#define TSTR 24               // LDS tile row stride -> uniform 2-way (free)

__device__ inline unsigned f2key(float f) {
    unsigned u = __float_as_uint(f);
    return (u & 0x80000000u) ? ~u : (u | 0x80000000u);
}
__device__ inline float key2f(unsigned k) {
    unsigned u = (k & 0x80000000u) ? (k ^ 0x80000000u) : ~k;
    return __uint_as_float(u);
}

// ---------- K0: rand/std (ddof=1); init keys; zero out -----------------------
__global__ __launch_bounds__(64) void k_rnorm(const float* __restrict__ rnd,
                                              float* __restrict__ rnorm,
                                              unsigned* __restrict__ keys,
                                              float* __restrict__ out) {
    int bp = blockIdx.x;
    int b = bp / NPROJ, p = bp % NPROJ;
    int lane = threadIdx.x;
    if (lane == 0) {
        keys[2 * bp] = 0xFFFFFFFFu;
        keys[2 * bp + 1] = 0u;
        if (bp == 0) out[0] = 0.f;     // accumulated atomically in k_gather
    }
    float s = 0.f, s2 = 0.f;
    for (int d = lane; d < DF; d += 64) {
        float v = rnd[((size_t)b * DF + d) * NPROJ + p];
        s += v; s2 += v * v;
    }
    for (int o = 32; o > 0; o >>= 1) { s += __shfl_down(s, o); s2 += __shfl_down(s2, o); }
    s = __shfl(s, 0); s2 = __shfl(s2, 0);
    float mean = s / (float)DF;
    float var = (s2 - (float)DF * mean * mean) / (float)(DF - 1);
    float inv = 1.0f / sqrtf(var);
    for (int d = lane; d < DF; d += 64) {
        size_t idx = ((size_t)b * DF + d) * NPROJ + p;
        rnorm[idx] = rnd[idx] * inv;
    }
}

// ---------- K1: proj both images; store px AND py; min/max atomics -----------
// tile 32(h)x16(w), 256 threads, 2 outputs/thread. grid (24,12,4): z=b*2+isy.
// Weights in LDS, read as 4x float4 wave-uniform broadcasts per (c,i,j).
#define T1H 32
#define T1W 16
__global__ __launch_bounds__(256) void k_projmm(const float* __restrict__ ximg,
                                                const float* __restrict__ yimg,
                                                const float* __restrict__ rnorm,
                                                float* __restrict__ px,
                                                float* __restrict__ py,
                                                unsigned* __restrict__ keys) {
    __shared__ float wlds[DF][NPROJ];           // 9408 B, 16B-aligned rows (64B stride)
    __shared__ float tile[C_][T1H + 6][TSTR];   // [3][38][24]
    __shared__ float red_mn[4][NPROJ], red_mx[4][NPROJ];
    int bz = blockIdx.z;
    int b = bz >> 1, isy = bz & 1;
    const float* img = isy ? yimg : ximg;
    float* proj = isy ? py : px;
    int tid = threadIdx.x;
    int tx = tid & 15, ty = tid >> 4;              // 16x16 threads, rows 16 apart
    int h0 = blockIdx.y * T1H, w0 = blockIdx.x * T1W;

    for (int i = tid; i < DF * NPROJ; i += 256)
        ((float*)wlds)[i] = rnorm[(size_t)b * DF * NPROJ + i];
    for (int c = 0; c < C_; c++)
        for (int i = tid; i < (T1H + 6) * (T1W + 6); i += 256) {
            int r = i / (T1W + 6), col = i % (T1W + 6);
            int h = h0 + r, w = w0 + col;
            tile[c][r][col] = (h < H_ && w < W_)
                ? img[((size_t)(b * C_ + c) * H_ + h) * W_ + w] : 0.f;
        }
    __syncthreads();

    float acc[2][NPROJ];
#pragma unroll
    for (int q = 0; q < 2; q++)
#pragma unroll
        for (int p = 0; p < NPROJ; p++) acc[q][p] = 0.f;

    for (int c = 0; c < C_; c++)
        for (int i = 0; i < 7; i++)
#pragma unroll
            for (int j = 0; j < 7; j++) {
                const float4* wp4 = (const float4*)&wlds[c * 49 + i * 7 + j][0];
                float4 w0v = wp4[0], w1v = wp4[1], w2v = wp4[2], w3v = wp4[3];
                float wv[NPROJ] = { w0v.x, w0v.y, w0v.z, w0v.w,
                                    w1v.x, w1v.y, w1v.z, w1v.w,
                                    w2v.x, w2v.y, w2v.z, w2v.w,
                                    w3v.x, w3v.y, w3v.z, w3v.w };
                float pix0 = tile[c][ty + i][tx + j];
                float pix1 = tile[c][ty + 16 + i][tx + j];
#pragma unroll
                for (int p = 0; p < NPROJ; p++) {
                    acc[0][p] = fmaf(pix0, wv[p], acc[0][p]);
                    acc[1][p] = fmaf(pix1, wv[p], acc[1][p]);
                }
            }

    int wo = w0 + tx;
    int ho0 = h0 + ty, ho1 = h0 + ty + 16;
    bool vm0 = (ho0 < HO) && (wo < HO);
    bool vm1 = (ho1 < HO) && (wo < HO);

    if (vm0) {
        size_t n = (size_t)ho0 * HO + wo;
#pragma unroll
        for (int p = 0; p < NPROJ; p++)
            proj[((size_t)(b * NPROJ + p)) * NPAT + n] = acc[0][p];
    }
    if (vm1) {
        size_t n = (size_t)ho1 * HO + wo;
#pragma unroll
        for (int p = 0; p < NPROJ; p++)
            proj[((size_t)(b * NPROJ + p)) * NPAT + n] = acc[1][p];
    }

    float pmn[NPROJ], pmx[NPROJ];
#pragma unroll
    for (int p = 0; p < NPROJ; p++) {
        float mn = INFINITY, mx = -INFINITY;
        if (vm0) { mn = acc[0][p]; mx = acc[0][p]; }
        if (vm1) { mn = fminf(mn, acc[1][p]); mx = fmaxf(mx, acc[1][p]); }
        pmn[p] = mn; pmx[p] = mx;
    }
#pragma unroll
    for (int o = 1; o < 64; o <<= 1) {
#pragma unroll
        for (int p = 0; p < NPROJ; p++) {
            pmn[p] = fminf(pmn[p], __shfl_xor(pmn[p], o));
            pmx[p] = fmaxf(pmx[p], __shfl_xor(pmx[p], o));
        }
    }
    int wv4 = tid >> 6;
    if ((tid & 63) == 0) {
#pragma unroll
        for (int p = 0; p < NPROJ; p++) { red_mn[wv4][p] = pmn[p]; red_mx[wv4][p] = pmx[p]; }
    }
    __syncthreads();
    if (tid < NPROJ) {
        float mn = fminf(fminf(red_mn[0][tid], red_mn[1][tid]),
                         fminf(red_mn[2][tid], red_mn[3][tid]));
        float mx = fmaxf(fmaxf(red_mx[0][tid], red_mx[1][tid]),
                         fmaxf(red_mx[2][tid], red_mx[3][tid]));
        atomicMin(&keys[2 * (b * NPROJ + tid)], f2key(mn));
        atomicMax(&keys[2 * (b * NPROJ + tid) + 1], f2key(mx));
    }
}

// ---------- K2: y-hist scatter -> LDS bitmap, one atomicOr flush -------------
// grid (8, BP). bit (8+idx) == old hist byte (8+idx). OR is idempotent.
__global__ __launch_bounds__(256) void k_scatter(const float* __restrict__ py,
                                                 const unsigned* __restrict__ keys,
                                                 unsigned* __restrict__ bitmap) {
    __shared__ unsigned lbm[BMW];
    int bp = blockIdx.y;
    int tid = threadIdx.x;
    for (int i = tid; i < BMW; i += 256) lbm[i] = 0u;
    __syncthreads();

    float mn = key2f(keys[2 * bp]);
    float sc = key2f(keys[2 * bp + 1]) - mn;
    const float4* src = (const float4*)(py + (size_t)bp * NPAT);
    const int n4 = NPAT / 4;
    for (int i = blockIdx.x * blockDim.x + tid; i < n4;
         i += gridDim.x * blockDim.x) {
        float4 v = src[i];
        float vv[4] = { v.x, v.y, v.z, v.w };
#pragma unroll
        for (int j = 0; j < 4; j++) {
            int idx = (int)floorf(65535.f * (vv[j] - mn) / sc);
            int bit = 8 + min(max(idx, 0), 65535);
            atomicOr(&lbm[bit >> 5], 1u << (bit & 31));
        }
    }
    __syncthreads();
    unsigned* dst = bitmap + (size_t)bp * BMW;
    for (int i = tid; i < BMW; i += 256) {
        unsigned w = lbm[i];
        if (w) atomicOr(&dst[i], w);
    }
}

// ---------- K3: gather via LDS-staged bitmap + 256-entry LDS LUT -------------
__global__ __launch_bounds__(256) void k_gather(const float* __restrict__ px,
                                                const unsigned* __restrict__ keys,
                                                const unsigned* __restrict__ bitmap,
                                                float* __restrict__ out) {
    __shared__ unsigned lbm[BMW];
    __shared__ float2 lut[256];
    __shared__ float sred[4];
    int bp = blockIdx.y;
    int tid = threadIdx.x;

    const unsigned* gbm = bitmap + (size_t)bp * BMW;
    for (int i = tid; i < BMW; i += 256) lbm[i] = gbm[i];

    float g[7];
#pragma unroll
    for (int k = 0; k < 7; k++) {
        float d = (float)(k - 3);
        g[k] = expf(-(d * d) / 1.44f);   // exp((x)^2/(-2*1.2^2))**2
    }
    {
        int m = tid;   // 256 threads -> one LUT entry each
        float f[8];
#pragma unroll
        for (int k = 0; k < 8; k++) f[k] = (float)((m >> k) & 1);
        float s0 = g[0] * f[0] + g[1] * f[1] + g[2] * f[2] + g[3] * f[3]
                 + g[4] * f[4] + g[5] * f[5] + g[6] * f[6];
        float s1 = g[0] * f[1] + g[1] * f[2] + g[2] * f[3] + g[3] * f[4]
                 + g[4] * f[5] + g[5] * f[6] + g[6] * f[7];
        lut[m] = make_float2(fminf(s0, 1.f), fminf(s1, 1.f));
    }
    __syncthreads();

    float mn = key2f(keys[2 * bp]);
    float sc = key2f(keys[2 * bp + 1]) - mn;
    const float4* src = (const float4*)(px + (size_t)bp * NPAT);

    float acc = 0.f;
    const int n4 = NPAT / 4;
    for (int i = blockIdx.x * blockDim.x + tid; i < n4;
         i += gridDim.x * blockDim.x) {
        float4 v4 = src[i];
        float vv[4] = { v4.x, v4.y, v4.z, v4.w };
#pragma unroll
        for (int j = 0; j < 4; j++) {
            float v = vv[j];
            float t = (v - mn) / sc;             // in [0,1]
            float ix = t * (float)WD - 0.5f;
            float x0 = floorf(ix);
            float w1 = ix - x0;
            int x0i = (int)x0;                   // [-1, WD-1]
            int bit0 = 8 + x0i;                  // [7, 65536]
            int w = bit0 >> 5, s = bit0 & 31;
            uint64_t d = (uint64_t)lbm[w] | ((uint64_t)lbm[w + 1] << 32);
            uint32_t w8 = (uint32_t)(d >> s) & 0xFFu;
            float2 sv = lut[w8];
            float r0 = (x0i >= 0) ? sv.x : 0.f;
            float r1 = (x0i + 1 < WD) ? sv.y : 0.f;
            acc += r0 * (1.f - w1) + r1 * w1;
        }
    }
    for (int o = 32; o > 0; o >>= 1) acc += __shfl_down(acc, o);
    int wv4 = tid >> 6;
    if ((tid & 63) == 0) sred[wv4] = acc;
    __syncthreads();
    if (tid == 0) {
        float t = sred[0] + sred[1] + sred[2] + sred[3];
        atomicAdd(out, -t * (1.0f / 32.0f));
    }
}

extern "C" void kernel_launch(void* const* d_in, const int* in_sizes, int n_in,
                              void* d_out, int out_size, void* d_ws, size_t ws_size,
                              hipStream_t stream) {
    (void)in_sizes; (void)n_in; (void)out_size; (void)ws_size;
    const float* x = (const float*)d_in[0];
    const float* y = (const float*)d_in[1];
    const float* rnd = (const float*)d_in[2];
    float* out = (float*)d_out;

    float* ws = (float*)d_ws;
    float* rnorm = ws;                                     // 4704 floats
    float* px = rnorm + (size_t)B_ * DF * NPROJ;           // BP*NPAT floats
    float* py = px + (size_t)BP * NPAT;                    // BP*NPAT floats
    unsigned* keys = (unsigned*)(py + (size_t)BP * NPAT);  // 2*BP
    unsigned* bitmap = keys + 2 * BP;                      // BP*BMW u32 (263 KB)

    k_rnorm<<<BP, 64, 0, stream>>>(rnd, rnorm, keys, out);
    hipMemsetAsync(bitmap, 0, (size_t)BP * BMW * sizeof(unsigned), stream);

    dim3 g1(384 / T1W, 384 / T1H, 2 * B_);                 // (24,12,4)
    k_projmm<<<g1, 256, 0, stream>>>(x, y, rnorm, px, py, keys);

    k_scatter<<<dim3(8, BP), 256, 0, stream>>>(py, keys, bitmap);
    k_gather<<<dim3(70, BP), 256, 0, stream>>>(px, keys, bitmap, out);
}